// Round 4
// baseline (225.293 us; speedup 1.0000x reference)
//
#include <hip/hip_runtime.h>
#include <math.h>

#define NP   132
#define NV   67            // Hermitian half-spectrum (0..66), 66 = Nyquist
#define NPP  (NP*NP)       // 17424
#define NCH  64
#define NIMG 256
#define NX   128
#define NO   256
#define TWO_PI 6.2831853071795864769f

// ws layout (floats):
//   H   : [NCH ][NV][132][2]   transfer fn, [c][v][u]
//   A   : [NIMG][132][68][2]   row-DFT of y, [row][v] (68 = padded 67)
//   U   : [NIMG][NV][132][2]   col-roundtrip result, [v][n0]
//   rho : [NIMG][NPP]          real correction image
static const size_t OFF_H   = 0;
static const size_t OFF_A   = OFF_H + (size_t)NCH*NV*NP*2;
static const size_t OFF_U   = OFF_A + (size_t)NIMG*NP*68*2;
static const size_t OFF_RHO = OFF_U + (size_t)NIMG*NV*NP*2;

// i-power sign/swap: multiplier i^p (g-form) or (-i)^p (f-form)
#define TR0(t) (t.x)
#define TI0(t) (t.y)
#define TR1(t) (-(t.y))
#define TI1(t) (t.x)
#define TR2(t) (-(t.x))
#define TI2(t) (-(t.y))
#define TR3(t) (t.y)
#define TI3(t) (-(t.x))
#define CMACF(xr, xi, dr, di, TRv, TIv) { xr += (dr)*(TRv) + (di)*(TIv); xi += (di)*(TRv) - (dr)*(TIv); }
#define CMACG(xr, xi, dr, di, TRv, TIv) { xr += (dr)*(TRv) - (di)*(TIv); xi += (di)*(TRv) + (dr)*(TIv); }
#define ROT() { float nt = t.x*c0 - t.y*s0; t.y = t.x*s0 + t.y*c0; t.x = nt; }

__global__ __launch_bounds__(256) void k_compute_H(
    const float* __restrict__ wgt, const float* __restrict__ bias,
    float2* __restrict__ H) {
  int idx = blockIdx.x * 256 + threadIdx.x;   // over NV*NP
  int c = blockIdx.y;
  if (idx >= NV*NP) return;
  int u = idx % NP, v = idx / NP;
  float k[3][3];
#pragma unroll
  for (int i = 0; i < 3; i++)
#pragma unroll
    for (int j = 0; j < 3; j++) k[i][j] = wgt[c*9 + i*3 + j];
  float invW = 0.f;
#pragma unroll
  for (int p0 = -1; p0 <= 1; p0++)
#pragma unroll
    for (int p1 = -1; p1 <= 1; p1++) {
      float s = 0.f;
#pragma unroll
      for (int i = 0; i < 3; i++)
#pragma unroll
        for (int j = 0; j < 3; j++) {
          int i2 = i - 2*p0, j2 = j - 2*p1;
          if (i2 >= 0 && i2 < 3 && j2 >= 0 && j2 < 3) s += k[i][j]*k[i2][j2];
        }
      float ang = TWO_PI * (float)(u*p0 + v*p1) / (float)NP;
      invW += s * cosf(ang);
    }
  float B00 = k[0][0]+k[0][1]+k[1][0]+k[1][1];
  float B10 = k[2][0]+k[2][1];
  float B01 = k[0][2]+k[1][2];
  float B11 = k[2][2];
  float su, cu, sv, cv, suv, cuv;
  sincosf(TWO_PI*(float)u/(float)NP, &su, &cu);
  sincosf(TWO_PI*(float)v/(float)NP, &sv, &cv);
  sincosf(TWO_PI*(float)(u+v)/(float)NP, &suv, &cuv);
  float Bre = B00 + B10*cu + B01*cv + B11*cuv;
  float Bim = -(B10*su + B01*sv + B11*suv);
  float alpha = 1.f/(1.f + expf(9.f - bias[c])) + 1e-5f;
  float d = invW + alpha;
  H[((size_t)c*NV + v)*NP + u] = make_float2((1.f - Bre)/d, (-Bim)/d);
}

#define RLST 7   // float4 stride per spectral/spatial row: 7 f4 = 14 rowpairs

// S1 row-DFT, two-for-one + radix-4 (132 = 4*33).
// Row pairs as complex z = y_even + i*y_odd; per lane (rpg 0..6, q 0..32):
// 4 complex sub-sums S_r[q] = sum_m z[4m+r] e^{-2pi i q m/33} for 2 rowpairs
// (one float4 channel pair), combine Z[q+33s] = sum_r (-i)^{sr} W^{-qr} S_r,
// LDS round-trip, then Hermitian separation E/O -> A rows.
__global__ __launch_bounds__(256, 5) void k_s1(
    const float* __restrict__ x, float2* __restrict__ A) {
  __shared__ __align__(16) float4 la[(NP+4)*RLST];
  float2* la2 = (float2*)la;
  int tid = threadIdx.x, img = blockIdx.y, row0 = blockIdx.x*28;
  const float* xim = x + (size_t)img*NX*NX;
  int rmax = NP - row0;                       // 28 or 20 (last block)
  for (int e = tid; e < NP*14; e += 256) {
    int n1 = e % NP, j = e / NP;              // j = rowpair 0..13
    float2 z = make_float2(0.f, 0.f);
    if (2*j + 1 < rmax) {
      int col = (n1 + 126) & 127;
      int ra = (row0 + 2*j + 126) & 127;
      int rb = (row0 + 2*j + 127) & 127;
      z = make_float2(xim[ra*NX + col], xim[rb*NX + col]);
    }
    la2[n1*14 + j] = z;
  }
  __syncthreads();
  int rpg = tid / 33, q = tid - rpg*33;
  int nr = rmax >> 2; if (nr > 7) nr = 7;
  bool act = (tid < 231) && (rpg < nr);
  float s33, c33; sincosf(TWO_PI*(float)q/33.f, &s33, &c33);
  float Sr[4][2], Si[4][2];
#pragma unroll
  for (int r = 0; r < 4; r++) { Sr[r][0]=0.f; Sr[r][1]=0.f; Si[r][0]=0.f; Si[r][1]=0.f; }
  if (act) {
    const float4* bp = la + rpg;
    float4 a0 = bp[0], a1 = bp[RLST], a2 = bp[2*RLST], a3 = bp[3*RLST];
    float tr = 1.f, ti = 0.f;
#pragma unroll 1
    for (int m = 0; m < 33; ++m) {
      bp += 4*RLST;
      float4 b0 = bp[0], b1 = bp[RLST], b2 = bp[2*RLST], b3 = bp[3*RLST];
      CMACF(Sr[0][0], Si[0][0], a0.x, a0.y, tr, ti);
      CMACF(Sr[0][1], Si[0][1], a0.z, a0.w, tr, ti);
      CMACF(Sr[1][0], Si[1][0], a1.x, a1.y, tr, ti);
      CMACF(Sr[1][1], Si[1][1], a1.z, a1.w, tr, ti);
      CMACF(Sr[2][0], Si[2][0], a2.x, a2.y, tr, ti);
      CMACF(Sr[2][1], Si[2][1], a2.z, a2.w, tr, ti);
      CMACF(Sr[3][0], Si[3][0], a3.x, a3.y, tr, ti);
      CMACF(Sr[3][1], Si[3][1], a3.z, a3.w, tr, ti);
      float nt = tr*c33 - ti*s33; ti = tr*s33 + ti*c33; tr = nt;
      a0 = b0; a1 = b1; a2 = b2; a3 = b3;
    }
  }
  __syncthreads();   // all input reads done before overwrite
  if (act) {
    float sw, cw; sincosf(TWO_PI*(float)q/132.f, &sw, &cw);
    float2 w1 = make_float2(cw, sw);
    float2 w2 = make_float2(cw*cw - sw*sw, 2.f*cw*sw);
    float2 w3 = make_float2(w2.x*cw - w2.y*sw, w2.x*sw + w2.y*cw);
#define COMB1(sidx, P1, P2, P3) { \
    float z0r = Sr[0][0], z0i = Si[0][0], z1r = Sr[0][1], z1i = Si[0][1]; \
    CMACF(z0r, z0i, Sr[1][0], Si[1][0], TR##P1(w1), TI##P1(w1)); \
    CMACF(z1r, z1i, Sr[1][1], Si[1][1], TR##P1(w1), TI##P1(w1)); \
    CMACF(z0r, z0i, Sr[2][0], Si[2][0], TR##P2(w2), TI##P2(w2)); \
    CMACF(z1r, z1i, Sr[2][1], Si[2][1], TR##P2(w2), TI##P2(w2)); \
    CMACF(z0r, z0i, Sr[3][0], Si[3][0], TR##P3(w3), TI##P3(w3)); \
    CMACF(z1r, z1i, Sr[3][1], Si[3][1], TR##P3(w3), TI##P3(w3)); \
    la[(q + 33*sidx)*RLST + rpg] = make_float4(z0r, z0i, z1r, z1i); }
    COMB1(0,0,0,0) COMB1(1,1,2,3) COMB1(2,2,0,2) COMB1(3,3,2,1)
#undef COMB1
  }
  __syncthreads();   // Z visible
  if (act) {
    float2* Aim = A + (size_t)img*NP*68;
    int rbase = row0 + rpg*4;
    float4 Za = la[q*RLST + rpg];                      // Z[q]
    float4 Zb = la[((NP - q) % NP)*RLST + rpg];        // Z[132-q]
    float4 Zc = la[(q + 33)*RLST + rpg];               // Z[q+33]
    float4 Zd = la[(99 - q)*RLST + rpg];               // Z[99-q]
    // v = q : E = (Zv + conj(Zm))/2 ; O = (Im Zv + Im Zm, Re Zm - Re Zv)/2
    Aim[(size_t)(rbase+0)*68 + q] = make_float2(0.5f*(Za.x+Zb.x), 0.5f*(Za.y-Zb.y));
    Aim[(size_t)(rbase+1)*68 + q] = make_float2(0.5f*(Za.y+Zb.y), 0.5f*(Zb.x-Za.x));
    Aim[(size_t)(rbase+2)*68 + q] = make_float2(0.5f*(Za.z+Zb.z), 0.5f*(Za.w-Zb.w));
    Aim[(size_t)(rbase+3)*68 + q] = make_float2(0.5f*(Za.w+Zb.w), 0.5f*(Zb.z-Za.z));
    int v2 = q + 33;
    Aim[(size_t)(rbase+0)*68 + v2] = make_float2(0.5f*(Zc.x+Zd.x), 0.5f*(Zc.y-Zd.y));
    Aim[(size_t)(rbase+1)*68 + v2] = make_float2(0.5f*(Zc.y+Zd.y), 0.5f*(Zd.x-Zc.x));
    Aim[(size_t)(rbase+2)*68 + v2] = make_float2(0.5f*(Zc.z+Zd.z), 0.5f*(Zc.w-Zd.w));
    Aim[(size_t)(rbase+3)*68 + v2] = make_float2(0.5f*(Zc.w+Zd.w), 0.5f*(Zd.z-Zc.z));
    if (q == 0) {                                      // v = 66: A real = Z[66] parts
      float4 Ze = la[66*RLST + rpg];
      Aim[(size_t)(rbase+0)*68 + 66] = make_float2(Ze.x, 0.f);
      Aim[(size_t)(rbase+1)*68 + 66] = make_float2(Ze.y, 0.f);
      Aim[(size_t)(rbase+2)*68 + 66] = make_float2(Ze.z, 0.f);
      Aim[(size_t)(rbase+3)*68 + 66] = make_float2(Ze.w, 0.f);
    }
  }
}

// Fused S2+S3, radix-4 Cooley-Tukey (132 = 4*33), in-place LDS round-trip.
// 128-thread block, ONE 14-v strip of one image: 119 active lanes
// (jj 0..6 [2 v each] x qq 0..16); grid 5x256 = 1280 blocks = 5 blocks/CU,
// all co-resident (15.2 KB LDS, 4 waves/EU bound) -> ~2.3 compute waves/SIMD.
// Each lane: q in {qq, qq+17} (qq=16's partner q'=33 is a phantom: computed
// but never written; coverage of q=0..32 stays exact).
#define LSTRIDE 14
__global__ __launch_bounds__(128, 4) void k_s23(
    const float2* __restrict__ A, const float2* __restrict__ H,
    float2* __restrict__ U) {
  __shared__ __align__(16) float2 la[(NP+4)*LSTRIDE];  // [n0|u][14 v] + 4 pad rows
  int tid = threadIdx.x, img = blockIdx.y, v0 = blockIdx.x*14;
  int c = img & 63;
  for (int e = tid; e < NP*14; e += 128) {
    int n0 = e/14, j = e - n0*14;
    int v = v0 + j;
    la[n0*LSTRIDE + j] = (v < NV) ? A[((size_t)img*NP + n0)*68 + v] : make_float2(0.f, 0.f);
  }
  __syncthreads();
  bool act = (tid < 119);                    // 7 jj * 17 qq
  int jj = 0, qq = 0;
  if (act) { jj = tid/17; qq = tid - jj*17; }
  int q2 = qq + 17;
  bool ph2 = (q2 >= 33);                     // phantom partner (qq==16)
  float s33a, c33a, s33b, c33b;
  sincosf(TWO_PI*(float)qq/33.f, &s33a, &c33a);
  sincosf(TWO_PI*(float)q2/33.f, &s33b, &c33b);
  float Sr[4][2][2], Si[4][2][2];            // [r][qsel][w]
  const float2* lap = la + jj*2;
  const float2* Hc = H + (size_t)c*NV*NP;

#define RAD4(MAC, dd, r) \
      MAC(Sr[r][0][0], Si[r][0][0], dd.x, dd.y, t1r, t1i); \
      MAC(Sr[r][0][1], Si[r][0][1], dd.z, dd.w, t1r, t1i); \
      MAC(Sr[r][1][0], Si[r][1][0], dd.x, dd.y, t2r, t2i); \
      MAC(Sr[r][1][1], Si[r][1][1], dd.z, dd.w, t2r, t2i);

#define ZERO_S() { \
    _Pragma("unroll") for (int r = 0; r < 4; ++r) \
    _Pragma("unroll") for (int g = 0; g < 2; ++g) \
    _Pragma("unroll") for (int w = 0; w < 2; ++w) { Sr[r][g][w] = 0.f; Si[r][g][w] = 0.f; } }

#define RADIX4_LOOP(MAC) { \
    float t1r = 1.f, t1i = 0.f, t2r = 1.f, t2i = 0.f; \
    const float2* bp = lap; \
    float4 a0 = *(const float4*)(bp); \
    float4 a1 = *(const float4*)(bp + LSTRIDE); \
    float4 a2 = *(const float4*)(bp + 2*LSTRIDE); \
    float4 a3 = *(const float4*)(bp + 3*LSTRIDE); \
    _Pragma("unroll 1") \
    for (int m = 0; m < 33; ++m) { \
      bp += 4*LSTRIDE; \
      float4 b0 = *(const float4*)(bp); \
      float4 b1 = *(const float4*)(bp + LSTRIDE); \
      float4 b2 = *(const float4*)(bp + 2*LSTRIDE); \
      float4 b3 = *(const float4*)(bp + 3*LSTRIDE); \
      RAD4(MAC, a0, 0) RAD4(MAC, a1, 1) RAD4(MAC, a2, 2) RAD4(MAC, a3, 3) \
      { float nt = t1r*c33a - t1i*s33a; t1i = t1r*s33a + t1i*c33a; t1r = nt; } \
      { float nt = t2r*c33b - t2i*s33b; t2i = t2r*s33b + t2i*c33b; t2r = nt; } \
      a0 = b0; a1 = b1; a2 = b2; a3 = b3; \
    } }

  // ---- phase A: forward col-DFT (f-form: multiplier conj(t)) ----
  ZERO_S();
  if (act) RADIX4_LOOP(CMACF);
  __syncthreads();   // all reads of la complete
  // ---- combine + H-mult, write T[u][j] into la ----
  if (act) {
#pragma unroll
    for (int g = 0; g < 2; ++g) {
      if (g == 1 && ph2) continue;
      int q = g ? q2 : qq;
      float sw, cw; sincosf(TWO_PI*(float)q/132.f, &sw, &cw);
      float2 w1v = make_float2(cw, sw);
      float2 w2v = make_float2(cw*cw - sw*sw, 2.f*cw*sw);
      float2 w3v = make_float2(w2v.x*cw - w2v.y*sw, w2v.x*sw + w2v.y*cw);
#define COMBA(s, P1, P2, P3) { \
      int u = q + 33*(s); \
      _Pragma("unroll") \
      for (int w = 0; w < 2; ++w) { \
        float xr = Sr[0][g][w], xi = Si[0][g][w]; \
        CMACF(xr, xi, Sr[1][g][w], Si[1][g][w], TR##P1(w1v), TI##P1(w1v)); \
        CMACF(xr, xi, Sr[2][g][w], Si[2][g][w], TR##P2(w2v), TI##P2(w2v)); \
        CMACF(xr, xi, Sr[3][g][w], Si[3][g][w], TR##P3(w3v), TI##P3(w3v)); \
        int v = v0 + jj*2 + w; \
        float2 o = make_float2(0.f, 0.f); \
        if (v < NV) { float2 h = Hc[(size_t)v*NP + u]; \
          o = make_float2(xr*h.x - xi*h.y, xr*h.y + xi*h.x); } \
        la[u*LSTRIDE + jj*2 + w] = o; \
      } }
      COMBA(0,0,0,0) COMBA(1,1,2,3) COMBA(2,2,0,2) COMBA(3,3,2,1)
#undef COMBA
    }
  }
  __syncthreads();   // T visible
  // ---- phase B: inverse col-DFT (g-form: multiplier t) ----
  ZERO_S();
  if (act) {
    RADIX4_LOOP(CMACG);
#pragma unroll
    for (int g = 0; g < 2; ++g) {
      if (g == 1 && ph2) continue;
      int q = g ? q2 : qq;
      float sw, cw; sincosf(TWO_PI*(float)q/132.f, &sw, &cw);
      float2 w1v = make_float2(cw, sw);
      float2 w2v = make_float2(cw*cw - sw*sw, 2.f*cw*sw);
      float2 w3v = make_float2(w2v.x*cw - w2v.y*sw, w2v.x*sw + w2v.y*cw);
#define COMBB(s, P1, P2, P3) { \
      int n0 = q + 33*(s); \
      _Pragma("unroll") \
      for (int w = 0; w < 2; ++w) { \
        float xr = Sr[0][g][w], xi = Si[0][g][w]; \
        CMACG(xr, xi, Sr[1][g][w], Si[1][g][w], TR##P1(w1v), TI##P1(w1v)); \
        CMACG(xr, xi, Sr[2][g][w], Si[2][g][w], TR##P2(w2v), TI##P2(w2v)); \
        CMACG(xr, xi, Sr[3][g][w], Si[3][g][w], TR##P3(w3v), TI##P3(w3v)); \
        int v = v0 + jj*2 + w; \
        if (v < NV) U[((size_t)img*NV + v)*NP + n0] = make_float2(xr, xi); \
      } }
      COMBB(0,0,0,0) COMBB(1,1,2,3) COMBB(2,2,0,2) COMBB(3,3,2,1)
#undef COMBB
    }
  }
#undef RADIX4_LOOP
#undef ZERO_S
#undef RAD4
}
#undef LSTRIDE

// S4: two-for-one inverse + radix-4. Row pairs of rho via Hermitian-extended
// spectrum W[v] = Ua_f[v] + i*Ub_f[v] (v 0..131); complex radix-4 IDFT;
// Re -> rho[row], Im -> rho[row+1]. Same lane map as k_s1, no round-trip.
__global__ __launch_bounds__(256, 5) void k_s4(
    const float2* __restrict__ U, float* __restrict__ rho) {
  __shared__ __align__(16) float4 lu[(NP+4)*RLST];
  float2* lu2 = (float2*)lu;
  int tid = threadIdx.x, img = blockIdx.y, row0 = blockIdx.x*28;
  int rmax = NP - row0;
  const float2* Uim = U + (size_t)img*NV*NP;
  for (int e = tid; e < NP*14; e += 256) {
    int v = e % NP, j = e / NP;
    float2 wv = make_float2(0.f, 0.f);
    if (2*j + 1 < rmax) {
      int row = row0 + 2*j;
      if (v < NV) {
        float2 ua = Uim[(size_t)v*NP + row];
        float2 ub = Uim[(size_t)v*NP + row + 1];
        wv = make_float2(ua.x - ub.y, ua.y + ub.x);
      } else {
        int vv = NP - v;   // 1..65
        float2 ua = Uim[(size_t)vv*NP + row];
        float2 ub = Uim[(size_t)vv*NP + row + 1];
        wv = make_float2(ua.x + ub.y, ub.x - ua.y);
      }
    }
    lu2[v*14 + j] = wv;
  }
  __syncthreads();
  int rpg = tid / 33, q = tid - rpg*33;
  int nr = rmax >> 2; if (nr > 7) nr = 7;
  bool act = (tid < 231) && (rpg < nr);
  float s33, c33; sincosf(TWO_PI*(float)q/33.f, &s33, &c33);
  float Sr[4][2], Si[4][2];
#pragma unroll
  for (int r = 0; r < 4; r++) { Sr[r][0]=0.f; Sr[r][1]=0.f; Si[r][0]=0.f; Si[r][1]=0.f; }
  if (act) {
    const float4* bp = lu + rpg;
    float4 a0 = bp[0], a1 = bp[RLST], a2 = bp[2*RLST], a3 = bp[3*RLST];
    float tr = 1.f, ti = 0.f;
#pragma unroll 1
    for (int m = 0; m < 33; ++m) {
      bp += 4*RLST;
      float4 b0 = bp[0], b1 = bp[RLST], b2 = bp[2*RLST], b3 = bp[3*RLST];
      CMACG(Sr[0][0], Si[0][0], a0.x, a0.y, tr, ti);
      CMACG(Sr[0][1], Si[0][1], a0.z, a0.w, tr, ti);
      CMACG(Sr[1][0], Si[1][0], a1.x, a1.y, tr, ti);
      CMACG(Sr[1][1], Si[1][1], a1.z, a1.w, tr, ti);
      CMACG(Sr[2][0], Si[2][0], a2.x, a2.y, tr, ti);
      CMACG(Sr[2][1], Si[2][1], a2.z, a2.w, tr, ti);
      CMACG(Sr[3][0], Si[3][0], a3.x, a3.y, tr, ti);
      CMACG(Sr[3][1], Si[3][1], a3.z, a3.w, tr, ti);
      float nt = tr*c33 - ti*s33; ti = tr*s33 + ti*c33; tr = nt;
      a0 = b0; a1 = b1; a2 = b2; a3 = b3;
    }
  }
  if (act) {
    float sw, cw; sincosf(TWO_PI*(float)q/132.f, &sw, &cw);
    float2 w1 = make_float2(cw, sw);
    float2 w2 = make_float2(cw*cw - sw*sw, 2.f*cw*sw);
    float2 w3 = make_float2(w2.x*cw - w2.y*sw, w2.x*sw + w2.y*cw);
    float* rim = rho + (size_t)img*NPP;
    int rbase = row0 + rpg*4;
    const float scale = 1.0f/(float)NPP;
#define COMB4(sidx, P1, P2, P3) { \
    float z0r = Sr[0][0], z0i = Si[0][0], z1r = Sr[0][1], z1i = Si[0][1]; \
    CMACG(z0r, z0i, Sr[1][0], Si[1][0], TR##P1(w1), TI##P1(w1)); \
    CMACG(z1r, z1i, Sr[1][1], Si[1][1], TR##P1(w1), TI##P1(w1)); \
    CMACG(z0r, z0i, Sr[2][0], Si[2][0], TR##P2(w2), TI##P2(w2)); \
    CMACG(z1r, z1i, Sr[2][1], Si[2][1], TR##P2(w2), TI##P2(w2)); \
    CMACG(z0r, z0i, Sr[3][0], Si[3][0], TR##P3(w3), TI##P3(w3)); \
    CMACG(z1r, z1i, Sr[3][1], Si[3][1], TR##P3(w3), TI##P3(w3)); \
    int n1 = q + 33*(sidx); \
    rim[(size_t)(rbase+0)*NP + n1] = z0r*scale; \
    rim[(size_t)(rbase+1)*NP + n1] = z0i*scale; \
    rim[(size_t)(rbase+2)*NP + n1] = z1r*scale; \
    rim[(size_t)(rbase+3)*NP + n1] = z1i*scale; }
    COMB4(0,0,0,0) COMB4(1,1,2,3) COMB4(2,2,0,2) COMB4(3,3,2,1)
#undef COMB4
  }
}
#undef RLST

// epilogue: out = gelu( x_up + subpixel 3x3 taps of K over zero-upsampled rho )
__global__ __launch_bounds__(256) void k_epilogue(
    const float* __restrict__ x, const float* __restrict__ wgt,
    const float* __restrict__ rho, float* __restrict__ out) {
  int idx = blockIdx.x * 256 + threadIdx.x;
  int o1 = idx & 255;
  int o0 = (idx >> 8) & 255;
  int img = idx >> 16;
  int c = img & 63;
  int n0 = (o0 + 4) >> 1, n1 = (o1 + 4) >> 1;
  int p0 = o0 & 1, p1 = o1 & 1;
  const float* rim = rho + (size_t)img*NPP;
  int base = n0*NP + n1;
  float r00 = rim[base], r01 = rim[base+1], r10 = rim[base+NP], r11 = rim[base+NP+1];
  const float* w = wgt + c*9;
  float wa = p0 ? (p1 ? w[0] : w[1]) : (p1 ? w[3] : w[4]);
  float wb = p1 ? (p0 ? w[2] : w[5]) : 0.f;
  float wc = p0 ? (p1 ? w[6] : w[7]) : 0.f;
  float wd = (p0 & p1) ? w[8] : 0.f;
  float S = wa*r00 + wb*r01 + wc*r10 + wd*r11;
  float xv = x[(size_t)img*NX*NX + (n0-2)*NX + (n1-2)];
  float z = xv + S;
  out[idx] = 0.5f*z*(1.0f + erff(z*0.70710678118654752f));
}

extern "C" void kernel_launch(void* const* d_in, const int* in_sizes, int n_in,
                              void* d_out, int out_size, void* d_ws, size_t ws_size,
                              hipStream_t stream) {
  const float* x    = (const float*)d_in[0];
  const float* wgt  = (const float*)d_in[1];
  const float* bias = (const float*)d_in[2];
  float* ws = (float*)d_ws;
  float2* H   = (float2*)(ws + OFF_H);
  float2* A   = (float2*)(ws + OFF_A);
  float2* U   = (float2*)(ws + OFF_U);
  float*  rho = ws + OFF_RHO;
  float* out = (float*)d_out;

  k_compute_H<<<dim3((NV*NP + 255)/256, NCH), 256, 0, stream>>>(wgt, bias, H);
  k_s1 <<<dim3(5, NIMG), 256, 0, stream>>>(x, A);      // 5*28 >= 132 rows (2-for-1 radix-4)
  k_s23<<<dim3(5, NIMG), 128, 0, stream>>>(A, H, U);   // 128-thr blocks, 5*14 >= 67 v
  k_s4 <<<dim3(5, NIMG), 256, 0, stream>>>(U, rho);    // 5*28 >= 132 rows (2-for-1 radix-4)
  k_epilogue<<<(NIMG*NO*NO)/256, 256, 0, stream>>>(x, wgt, rho, out);
}

// Round 5
// 215.057 us; speedup vs baseline: 1.0476x; 1.0476x over previous
//
#include <hip/hip_runtime.h>
#include <math.h>

#define NP   132
#define NV   67            // Hermitian half-spectrum (0..66), 66 = Nyquist
#define NPP  (NP*NP)       // 17424
#define NCH  64
#define NIMG 256
#define NX   128
#define NO   256
#define TWO_PI 6.2831853071795864769f

// ws layout (floats):
//   H   : [NCH ][NV][132][2]   transfer fn, [c][v][u]
//   A   : [NIMG][132][68][2]   row-DFT of y, [row][v] (68 = padded 67)
//   U   : [NIMG][NV][132][2]   col-roundtrip result, [v][n0]
//   rho : [NIMG][NPP]          real correction image
static const size_t OFF_H   = 0;
static const size_t OFF_A   = OFF_H + (size_t)NCH*NV*NP*2;
static const size_t OFF_U   = OFF_A + (size_t)NIMG*NP*68*2;
static const size_t OFF_RHO = OFF_U + (size_t)NIMG*NV*NP*2;

// i-power sign/swap: multiplier i^p (g-form) or (-i)^p (f-form)
#define TR0(t) (t.x)
#define TI0(t) (t.y)
#define TR1(t) (-(t.y))
#define TI1(t) (t.x)
#define TR2(t) (-(t.x))
#define TI2(t) (-(t.y))
#define TR3(t) (t.y)
#define TI3(t) (-(t.x))
#define CMACF(xr, xi, dr, di, TRv, TIv) { xr += (dr)*(TRv) + (di)*(TIv); xi += (di)*(TRv) - (dr)*(TIv); }
#define CMACG(xr, xi, dr, di, TRv, TIv) { xr += (dr)*(TRv) - (di)*(TIv); xi += (di)*(TRv) + (dr)*(TIv); }
#define ROT() { float nt = t.x*c0 - t.y*s0; t.y = t.x*s0 + t.y*c0; t.x = nt; }

__global__ __launch_bounds__(256) void k_compute_H(
    const float* __restrict__ wgt, const float* __restrict__ bias,
    float2* __restrict__ H) {
  int idx = blockIdx.x * 256 + threadIdx.x;   // over NV*NP
  int c = blockIdx.y;
  if (idx >= NV*NP) return;
  int u = idx % NP, v = idx / NP;
  float k[3][3];
#pragma unroll
  for (int i = 0; i < 3; i++)
#pragma unroll
    for (int j = 0; j < 3; j++) k[i][j] = wgt[c*9 + i*3 + j];
  float invW = 0.f;
#pragma unroll
  for (int p0 = -1; p0 <= 1; p0++)
#pragma unroll
    for (int p1 = -1; p1 <= 1; p1++) {
      float s = 0.f;
#pragma unroll
      for (int i = 0; i < 3; i++)
#pragma unroll
        for (int j = 0; j < 3; j++) {
          int i2 = i - 2*p0, j2 = j - 2*p1;
          if (i2 >= 0 && i2 < 3 && j2 >= 0 && j2 < 3) s += k[i][j]*k[i2][j2];
        }
      float ang = TWO_PI * (float)(u*p0 + v*p1) / (float)NP;
      invW += s * cosf(ang);
    }
  float B00 = k[0][0]+k[0][1]+k[1][0]+k[1][1];
  float B10 = k[2][0]+k[2][1];
  float B01 = k[0][2]+k[1][2];
  float B11 = k[2][2];
  float su, cu, sv, cv, suv, cuv;
  sincosf(TWO_PI*(float)u/(float)NP, &su, &cu);
  sincosf(TWO_PI*(float)v/(float)NP, &sv, &cv);
  sincosf(TWO_PI*(float)(u+v)/(float)NP, &suv, &cuv);
  float Bre = B00 + B10*cu + B01*cv + B11*cuv;
  float Bim = -(B10*su + B01*sv + B11*suv);
  float alpha = 1.f/(1.f + expf(9.f - bias[c])) + 1e-5f;
  float d = invW + alpha;
  H[((size_t)c*NV + v)*NP + u] = make_float2((1.f - Bre)/d, (-Bim)/d);
}

#define RLST 7   // float4 stride per spectral/spatial row: 7 f4 = 14 rowpairs

// S1 row-DFT, two-for-one + radix-4 (132 = 4*33).
// Row pairs as complex z = y_even + i*y_odd; per lane (rpg 0..6, q 0..32):
// 4 complex sub-sums S_r[q] = sum_m z[4m+r] e^{-2pi i q m/33} for 2 rowpairs
// (one float4 channel pair), combine Z[q+33s] = sum_r (-i)^{sr} W^{-qr} S_r,
// LDS round-trip, then Hermitian separation E/O -> A rows.
__global__ __launch_bounds__(256, 5) void k_s1(
    const float* __restrict__ x, float2* __restrict__ A) {
  __shared__ __align__(16) float4 la[(NP+4)*RLST];
  float2* la2 = (float2*)la;
  int tid = threadIdx.x, img = blockIdx.y, row0 = blockIdx.x*28;
  const float* xim = x + (size_t)img*NX*NX;
  int rmax = NP - row0;                       // 28 or 20 (last block)
  for (int e = tid; e < NP*14; e += 256) {
    int n1 = e % NP, j = e / NP;              // j = rowpair 0..13
    float2 z = make_float2(0.f, 0.f);
    if (2*j + 1 < rmax) {
      int col = (n1 + 126) & 127;
      int ra = (row0 + 2*j + 126) & 127;
      int rb = (row0 + 2*j + 127) & 127;
      z = make_float2(xim[ra*NX + col], xim[rb*NX + col]);
    }
    la2[n1*14 + j] = z;
  }
  __syncthreads();
  int rpg = tid / 33, q = tid - rpg*33;
  int nr = rmax >> 2; if (nr > 7) nr = 7;
  bool act = (tid < 231) && (rpg < nr);
  float s33, c33; sincosf(TWO_PI*(float)q/33.f, &s33, &c33);
  float Sr[4][2], Si[4][2];
#pragma unroll
  for (int r = 0; r < 4; r++) { Sr[r][0]=0.f; Sr[r][1]=0.f; Si[r][0]=0.f; Si[r][1]=0.f; }
  if (act) {
    const float4* bp = la + rpg;
    float4 a0 = bp[0], a1 = bp[RLST], a2 = bp[2*RLST], a3 = bp[3*RLST];
    float tr = 1.f, ti = 0.f;
#pragma unroll 1
    for (int m = 0; m < 33; ++m) {
      bp += 4*RLST;
      float4 b0 = bp[0], b1 = bp[RLST], b2 = bp[2*RLST], b3 = bp[3*RLST];
      CMACF(Sr[0][0], Si[0][0], a0.x, a0.y, tr, ti);
      CMACF(Sr[0][1], Si[0][1], a0.z, a0.w, tr, ti);
      CMACF(Sr[1][0], Si[1][0], a1.x, a1.y, tr, ti);
      CMACF(Sr[1][1], Si[1][1], a1.z, a1.w, tr, ti);
      CMACF(Sr[2][0], Si[2][0], a2.x, a2.y, tr, ti);
      CMACF(Sr[2][1], Si[2][1], a2.z, a2.w, tr, ti);
      CMACF(Sr[3][0], Si[3][0], a3.x, a3.y, tr, ti);
      CMACF(Sr[3][1], Si[3][1], a3.z, a3.w, tr, ti);
      float nt = tr*c33 - ti*s33; ti = tr*s33 + ti*c33; tr = nt;
      a0 = b0; a1 = b1; a2 = b2; a3 = b3;
    }
  }
  __syncthreads();   // all input reads done before overwrite
  if (act) {
    float sw, cw; sincosf(TWO_PI*(float)q/132.f, &sw, &cw);
    float2 w1 = make_float2(cw, sw);
    float2 w2 = make_float2(cw*cw - sw*sw, 2.f*cw*sw);
    float2 w3 = make_float2(w2.x*cw - w2.y*sw, w2.x*sw + w2.y*cw);
#define COMB1(sidx, P1, P2, P3) { \
    float z0r = Sr[0][0], z0i = Si[0][0], z1r = Sr[0][1], z1i = Si[0][1]; \
    CMACF(z0r, z0i, Sr[1][0], Si[1][0], TR##P1(w1), TI##P1(w1)); \
    CMACF(z1r, z1i, Sr[1][1], Si[1][1], TR##P1(w1), TI##P1(w1)); \
    CMACF(z0r, z0i, Sr[2][0], Si[2][0], TR##P2(w2), TI##P2(w2)); \
    CMACF(z1r, z1i, Sr[2][1], Si[2][1], TR##P2(w2), TI##P2(w2)); \
    CMACF(z0r, z0i, Sr[3][0], Si[3][0], TR##P3(w3), TI##P3(w3)); \
    CMACF(z1r, z1i, Sr[3][1], Si[3][1], TR##P3(w3), TI##P3(w3)); \
    la[(q + 33*sidx)*RLST + rpg] = make_float4(z0r, z0i, z1r, z1i); }
    COMB1(0,0,0,0) COMB1(1,1,2,3) COMB1(2,2,0,2) COMB1(3,3,2,1)
#undef COMB1
  }
  __syncthreads();   // Z visible
  if (act) {
    float2* Aim = A + (size_t)img*NP*68;
    int rbase = row0 + rpg*4;
    float4 Za = la[q*RLST + rpg];                      // Z[q]
    float4 Zb = la[((NP - q) % NP)*RLST + rpg];        // Z[132-q]
    float4 Zc = la[(q + 33)*RLST + rpg];               // Z[q+33]
    float4 Zd = la[(99 - q)*RLST + rpg];               // Z[99-q]
    // v = q : E = (Zv + conj(Zm))/2 ; O = (Im Zv + Im Zm, Re Zm - Re Zv)/2
    Aim[(size_t)(rbase+0)*68 + q] = make_float2(0.5f*(Za.x+Zb.x), 0.5f*(Za.y-Zb.y));
    Aim[(size_t)(rbase+1)*68 + q] = make_float2(0.5f*(Za.y+Zb.y), 0.5f*(Zb.x-Za.x));
    Aim[(size_t)(rbase+2)*68 + q] = make_float2(0.5f*(Za.z+Zb.z), 0.5f*(Za.w-Zb.w));
    Aim[(size_t)(rbase+3)*68 + q] = make_float2(0.5f*(Za.w+Zb.w), 0.5f*(Zb.z-Za.z));
    int v2 = q + 33;
    Aim[(size_t)(rbase+0)*68 + v2] = make_float2(0.5f*(Zc.x+Zd.x), 0.5f*(Zc.y-Zd.y));
    Aim[(size_t)(rbase+1)*68 + v2] = make_float2(0.5f*(Zc.y+Zd.y), 0.5f*(Zd.x-Zc.x));
    Aim[(size_t)(rbase+2)*68 + v2] = make_float2(0.5f*(Zc.z+Zd.z), 0.5f*(Zc.w-Zd.w));
    Aim[(size_t)(rbase+3)*68 + v2] = make_float2(0.5f*(Zc.w+Zd.w), 0.5f*(Zd.z-Zc.z));
    if (q == 0) {                                      // v = 66: A real = Z[66] parts
      float4 Ze = la[66*RLST + rpg];
      Aim[(size_t)(rbase+0)*68 + 66] = make_float2(Ze.x, 0.f);
      Aim[(size_t)(rbase+1)*68 + 66] = make_float2(Ze.y, 0.f);
      Aim[(size_t)(rbase+2)*68 + 66] = make_float2(Ze.z, 0.f);
      Aim[(size_t)(rbase+3)*68 + 66] = make_float2(Ze.w, 0.f);
    }
  }
}

// Fused S2+S3, radix-4 Cooley-Tukey (132 = 4*33), in-place LDS round-trip.
// ONE q per lane: (jj 0..6 [2 v each]) x (q 0..32) = 231/256 active lanes.
// Per-lane critical path: 33 m-steps x {4 ds_read_b128 + 8 CMAC + 1 rot}
// per phase (half of the previous 2-q packing). 5 blocks/CU co-resident.
#define LSTRIDE 14
__global__ __launch_bounds__(256, 5) void k_s23(
    const float2* __restrict__ A, const float2* __restrict__ H,
    float2* __restrict__ U) {
  __shared__ __align__(16) float2 la[(NP+4)*LSTRIDE];  // [n0|u][14 v] + 4 pad rows
  int tid = threadIdx.x, img = blockIdx.y, v0 = blockIdx.x*14;
  int c = img & 63;
  for (int e = tid; e < NP*14; e += 256) {
    int n0 = e/14, j = e - n0*14;
    int v = v0 + j;
    la[n0*LSTRIDE + j] = (v < NV) ? A[((size_t)img*NP + n0)*68 + v] : make_float2(0.f, 0.f);
  }
  __syncthreads();
  bool act = (tid < 231);                    // 7 jj * 33 q
  int jj = 0, q = 0;
  if (act) { jj = tid/33; q = tid - jj*33; }
  float s33, c33; sincosf(TWO_PI*(float)q/33.f, &s33, &c33);
  float sw, cw; sincosf(TWO_PI*(float)q/132.f, &sw, &cw);
  float2 w1v = make_float2(cw, sw);
  float2 w2v = make_float2(cw*cw - sw*sw, 2.f*cw*sw);
  float2 w3v = make_float2(w2v.x*cw - w2v.y*sw, w2v.x*sw + w2v.y*cw);
  float Sr[4][2], Si[4][2];                  // [r][w]
  const float2* lap = la + jj*2;
  const float2* Hc = H + (size_t)c*NV*NP;

#define RAD4(MAC, dd, r) \
      MAC(Sr[r][0], Si[r][0], dd.x, dd.y, tr, ti); \
      MAC(Sr[r][1], Si[r][1], dd.z, dd.w, tr, ti);

#define ZERO_S() { \
    _Pragma("unroll") for (int r = 0; r < 4; ++r) \
    _Pragma("unroll") for (int w = 0; w < 2; ++w) { Sr[r][w] = 0.f; Si[r][w] = 0.f; } }

#define RADIX4_LOOP(MAC) { \
    float tr = 1.f, ti = 0.f; \
    const float2* bp = lap; \
    float4 a0 = *(const float4*)(bp); \
    float4 a1 = *(const float4*)(bp + LSTRIDE); \
    float4 a2 = *(const float4*)(bp + 2*LSTRIDE); \
    float4 a3 = *(const float4*)(bp + 3*LSTRIDE); \
    _Pragma("unroll 1") \
    for (int m = 0; m < 33; ++m) { \
      bp += 4*LSTRIDE; \
      float4 b0 = *(const float4*)(bp); \
      float4 b1 = *(const float4*)(bp + LSTRIDE); \
      float4 b2 = *(const float4*)(bp + 2*LSTRIDE); \
      float4 b3 = *(const float4*)(bp + 3*LSTRIDE); \
      RAD4(MAC, a0, 0) RAD4(MAC, a1, 1) RAD4(MAC, a2, 2) RAD4(MAC, a3, 3) \
      { float nt = tr*c33 - ti*s33; ti = tr*s33 + ti*c33; tr = nt; } \
      a0 = b0; a1 = b1; a2 = b2; a3 = b3; \
    } }

  // ---- phase A: forward col-DFT (f-form: multiplier conj(t)) ----
  ZERO_S();
  if (act) RADIX4_LOOP(CMACF);
  __syncthreads();   // all reads of la complete
  // ---- combine + H-mult, write T[u][j] into la ----
  if (act) {
#define COMBA(s, P1, P2, P3) { \
      int u = q + 33*(s); \
      _Pragma("unroll") \
      for (int w = 0; w < 2; ++w) { \
        float xr = Sr[0][w], xi = Si[0][w]; \
        CMACF(xr, xi, Sr[1][w], Si[1][w], TR##P1(w1v), TI##P1(w1v)); \
        CMACF(xr, xi, Sr[2][w], Si[2][w], TR##P2(w2v), TI##P2(w2v)); \
        CMACF(xr, xi, Sr[3][w], Si[3][w], TR##P3(w3v), TI##P3(w3v)); \
        int v = v0 + jj*2 + w; \
        float2 o = make_float2(0.f, 0.f); \
        if (v < NV) { float2 h = Hc[(size_t)v*NP + u]; \
          o = make_float2(xr*h.x - xi*h.y, xr*h.y + xi*h.x); } \
        la[u*LSTRIDE + jj*2 + w] = o; \
      } }
    COMBA(0,0,0,0) COMBA(1,1,2,3) COMBA(2,2,0,2) COMBA(3,3,2,1)
#undef COMBA
  }
  __syncthreads();   // T visible
  // ---- phase B: inverse col-DFT (g-form: multiplier t) ----
  ZERO_S();
  if (act) {
    RADIX4_LOOP(CMACG);
#define COMBB(s, P1, P2, P3) { \
      int n0 = q + 33*(s); \
      _Pragma("unroll") \
      for (int w = 0; w < 2; ++w) { \
        float xr = Sr[0][w], xi = Si[0][w]; \
        CMACG(xr, xi, Sr[1][w], Si[1][w], TR##P1(w1v), TI##P1(w1v)); \
        CMACG(xr, xi, Sr[2][w], Si[2][w], TR##P2(w2v), TI##P2(w2v)); \
        CMACG(xr, xi, Sr[3][w], Si[3][w], TR##P3(w3v), TI##P3(w3v)); \
        int v = v0 + jj*2 + w; \
        if (v < NV) U[((size_t)img*NV + v)*NP + n0] = make_float2(xr, xi); \
      } }
    COMBB(0,0,0,0) COMBB(1,1,2,3) COMBB(2,2,0,2) COMBB(3,3,2,1)
#undef COMBB
  }
#undef RADIX4_LOOP
#undef ZERO_S
#undef RAD4
}
#undef LSTRIDE

// S4: two-for-one inverse + radix-4. Row pairs of rho via Hermitian-extended
// spectrum W[v] = Ua_f[v] + i*Ub_f[v] (v 0..131); complex radix-4 IDFT;
// Re -> rho[row], Im -> rho[row+1]. Same lane map as k_s1, no round-trip.
__global__ __launch_bounds__(256, 5) void k_s4(
    const float2* __restrict__ U, float* __restrict__ rho) {
  __shared__ __align__(16) float4 lu[(NP+4)*RLST];
  float2* lu2 = (float2*)lu;
  int tid = threadIdx.x, img = blockIdx.y, row0 = blockIdx.x*28;
  int rmax = NP - row0;
  const float2* Uim = U + (size_t)img*NV*NP;
  for (int e = tid; e < NP*14; e += 256) {
    int v = e % NP, j = e / NP;
    float2 wv = make_float2(0.f, 0.f);
    if (2*j + 1 < rmax) {
      int row = row0 + 2*j;
      if (v < NV) {
        float2 ua = Uim[(size_t)v*NP + row];
        float2 ub = Uim[(size_t)v*NP + row + 1];
        wv = make_float2(ua.x - ub.y, ua.y + ub.x);
      } else {
        int vv = NP - v;   // 1..65
        float2 ua = Uim[(size_t)vv*NP + row];
        float2 ub = Uim[(size_t)vv*NP + row + 1];
        wv = make_float2(ua.x + ub.y, ub.x - ua.y);
      }
    }
    lu2[v*14 + j] = wv;
  }
  __syncthreads();
  int rpg = tid / 33, q = tid - rpg*33;
  int nr = rmax >> 2; if (nr > 7) nr = 7;
  bool act = (tid < 231) && (rpg < nr);
  float s33, c33; sincosf(TWO_PI*(float)q/33.f, &s33, &c33);
  float Sr[4][2], Si[4][2];
#pragma unroll
  for (int r = 0; r < 4; r++) { Sr[r][0]=0.f; Sr[r][1]=0.f; Si[r][0]=0.f; Si[r][1]=0.f; }
  if (act) {
    const float4* bp = lu + rpg;
    float4 a0 = bp[0], a1 = bp[RLST], a2 = bp[2*RLST], a3 = bp[3*RLST];
    float tr = 1.f, ti = 0.f;
#pragma unroll 1
    for (int m = 0; m < 33; ++m) {
      bp += 4*RLST;
      float4 b0 = bp[0], b1 = bp[RLST], b2 = bp[2*RLST], b3 = bp[3*RLST];
      CMACG(Sr[0][0], Si[0][0], a0.x, a0.y, tr, ti);
      CMACG(Sr[0][1], Si[0][1], a0.z, a0.w, tr, ti);
      CMACG(Sr[1][0], Si[1][0], a1.x, a1.y, tr, ti);
      CMACG(Sr[1][1], Si[1][1], a1.z, a1.w, tr, ti);
      CMACG(Sr[2][0], Si[2][0], a2.x, a2.y, tr, ti);
      CMACG(Sr[2][1], Si[2][1], a2.z, a2.w, tr, ti);
      CMACG(Sr[3][0], Si[3][0], a3.x, a3.y, tr, ti);
      CMACG(Sr[3][1], Si[3][1], a3.z, a3.w, tr, ti);
      float nt = tr*c33 - ti*s33; ti = tr*s33 + ti*c33; tr = nt;
      a0 = b0; a1 = b1; a2 = b2; a3 = b3;
    }
  }
  if (act) {
    float sw, cw; sincosf(TWO_PI*(float)q/132.f, &sw, &cw);
    float2 w1 = make_float2(cw, sw);
    float2 w2 = make_float2(cw*cw - sw*sw, 2.f*cw*sw);
    float2 w3 = make_float2(w2.x*cw - w2.y*sw, w2.x*sw + w2.y*cw);
    float* rim = rho + (size_t)img*NPP;
    int rbase = row0 + rpg*4;
    const float scale = 1.0f/(float)NPP;
#define COMB4(sidx, P1, P2, P3) { \
    float z0r = Sr[0][0], z0i = Si[0][0], z1r = Sr[0][1], z1i = Si[0][1]; \
    CMACG(z0r, z0i, Sr[1][0], Si[1][0], TR##P1(w1), TI##P1(w1)); \
    CMACG(z1r, z1i, Sr[1][1], Si[1][1], TR##P1(w1), TI##P1(w1)); \
    CMACG(z0r, z0i, Sr[2][0], Si[2][0], TR##P2(w2), TI##P2(w2)); \
    CMACG(z1r, z1i, Sr[2][1], Si[2][1], TR##P2(w2), TI##P2(w2)); \
    CMACG(z0r, z0i, Sr[3][0], Si[3][0], TR##P3(w3), TI##P3(w3)); \
    CMACG(z1r, z1i, Sr[3][1], Si[3][1], TR##P3(w3), TI##P3(w3)); \
    int n1 = q + 33*(sidx); \
    rim[(size_t)(rbase+0)*NP + n1] = z0r*scale; \
    rim[(size_t)(rbase+1)*NP + n1] = z0i*scale; \
    rim[(size_t)(rbase+2)*NP + n1] = z1r*scale; \
    rim[(size_t)(rbase+3)*NP + n1] = z1i*scale; }
    COMB4(0,0,0,0) COMB4(1,1,2,3) COMB4(2,2,0,2) COMB4(3,3,2,1)
#undef COMB4
  }
}
#undef RLST

// epilogue: out = gelu( x_up + subpixel 3x3 taps of K over zero-upsampled rho )
__global__ __launch_bounds__(256) void k_epilogue(
    const float* __restrict__ x, const float* __restrict__ wgt,
    const float* __restrict__ rho, float* __restrict__ out) {
  int idx = blockIdx.x * 256 + threadIdx.x;
  int o1 = idx & 255;
  int o0 = (idx >> 8) & 255;
  int img = idx >> 16;
  int c = img & 63;
  int n0 = (o0 + 4) >> 1, n1 = (o1 + 4) >> 1;
  int p0 = o0 & 1, p1 = o1 & 1;
  const float* rim = rho + (size_t)img*NPP;
  int base = n0*NP + n1;
  float r00 = rim[base], r01 = rim[base+1], r10 = rim[base+NP], r11 = rim[base+NP+1];
  const float* w = wgt + c*9;
  float wa = p0 ? (p1 ? w[0] : w[1]) : (p1 ? w[3] : w[4]);
  float wb = p1 ? (p0 ? w[2] : w[5]) : 0.f;
  float wc = p0 ? (p1 ? w[6] : w[7]) : 0.f;
  float wd = (p0 & p1) ? w[8] : 0.f;
  float S = wa*r00 + wb*r01 + wc*r10 + wd*r11;
  float xv = x[(size_t)img*NX*NX + (n0-2)*NX + (n1-2)];
  float z = xv + S;
  out[idx] = 0.5f*z*(1.0f + erff(z*0.70710678118654752f));
}

extern "C" void kernel_launch(void* const* d_in, const int* in_sizes, int n_in,
                              void* d_out, int out_size, void* d_ws, size_t ws_size,
                              hipStream_t stream) {
  const float* x    = (const float*)d_in[0];
  const float* wgt  = (const float*)d_in[1];
  const float* bias = (const float*)d_in[2];
  float* ws = (float*)d_ws;
  float2* H   = (float2*)(ws + OFF_H);
  float2* A   = (float2*)(ws + OFF_A);
  float2* U   = (float2*)(ws + OFF_U);
  float*  rho = ws + OFF_RHO;
  float* out = (float*)d_out;

  k_compute_H<<<dim3((NV*NP + 255)/256, NCH), 256, 0, stream>>>(wgt, bias, H);
  k_s1 <<<dim3(5, NIMG), 256, 0, stream>>>(x, A);      // 5*28 >= 132 rows (2-for-1 radix-4)
  k_s23<<<dim3(5, NIMG), 256, 0, stream>>>(A, H, U);   // 1 q/lane, 231/256 active
  k_s4 <<<dim3(5, NIMG), 256, 0, stream>>>(U, rho);    // 5*28 >= 132 rows (2-for-1 radix-4)
  k_epilogue<<<(NIMG*NO*NO)/256, 256, 0, stream>>>(x, wgt, rho, out);
}